// Round 13
// baseline (331.612 us; speedup 1.0000x reference)
//
#include <hip/hip_runtime.h>

#define NNODES 65536
#define NDATA  32768
#define HID    128
#define HEADS  4
#define CHANS  32
#define LAYERS 4

using bf16x8 = __attribute__((ext_vector_type(8))) short;
using f32x4  = __attribute__((ext_vector_type(4))) float;

__device__ __forceinline__ float wave_reduce_sum(float v) {
#pragma unroll
    for (int m = 1; m < 64; m <<= 1) v += __shfl_xor(v, m, 64);
    return v;
}

__device__ __forceinline__ int wave_reduce_sum_i(int v) {
#pragma unroll
    for (int m = 1; m < 64; m <<= 1) v += __shfl_xor(v, m, 64);
    return v;
}

__device__ __forceinline__ unsigned short bf16_rne(float f) {
    unsigned u = __float_as_uint(f);
    return (unsigned short)((u + 0x7fffu + ((u >> 16) & 1u)) >> 16);
}
__device__ __forceinline__ float bf2f(unsigned short u) {
    return __uint_as_float((unsigned)u << 16);
}

__device__ __forceinline__ void gload_lds16(const unsigned short* g, unsigned short* l) {
    __builtin_amdgcn_global_load_lds(
        (const __attribute__((address_space(1))) void*)g,
        (__attribute__((address_space(3))) void*)l, 16, 0, 0);
}

// ---------------- CSR build ----------------
__global__ void hist_kernel(const int* __restrict__ ei, int* __restrict__ deg, int Eo) {
    int e = blockIdx.x * 256 + threadIdx.x;
    if (e >= Eo) return;
    atomicAdd(&deg[ei[Eo + e]], 1);   // dst row
}

// reads deg+1 (self-loop folded here; deg zeroed by memset)
__global__ void scan1(const int* __restrict__ deg, int* __restrict__ offs, int* __restrict__ bsum) {
    __shared__ int s[256];
    int t = threadIdx.x, b = blockIdx.x;
    int v = deg[b * 256 + t] + 1;
    s[t] = v;
    __syncthreads();
    for (int off = 1; off < 256; off <<= 1) {
        int add = (t >= off) ? s[t - off] : 0;
        __syncthreads();
        s[t] += add;
        __syncthreads();
    }
    offs[b * 256 + t] = s[t] - v;
    if (t == 255) bsum[b] = s[255];
}

// scan2 folded in: block b reduces bsum[0..b-1] itself (256 threads, masked)
__global__ void scan3(int* __restrict__ offs, const int* __restrict__ bsum,
                      int* __restrict__ cursor, int Eo) {
    __shared__ int ws[4];
    int b = blockIdx.x, t = threadIdx.x;
    int v = (t < b) ? bsum[t] : 0;
    v = wave_reduce_sum_i(v);
    if ((t & 63) == 0) ws[t >> 6] = v;
    __syncthreads();
    int base = ws[0] + ws[1] + ws[2] + ws[3];
    int i = b * 256 + t;
    int o = offs[i] + base;
    offs[i] = o;
    cursor[i] = o;
    if (i == 0) offs[NNODES] = Eo + NNODES;
}

__global__ void fill_kernel(const int* __restrict__ ei, int* __restrict__ cursor,
                            int* __restrict__ col, int Eo) {
    int e = blockIdx.x * 256 + threadIdx.x;
    int Etot = Eo + NNODES;
    if (e >= Etot) return;
    int src, dst;
    if (e < Eo) { src = ei[e]; dst = ei[Eo + e]; }
    else        { src = dst = e - Eo; }
    int pos = atomicAdd(&cursor[dst], 1);
    col[pos] = src;
}

// ------- merged: embedding (blocks 0..16383) + all weight prep (blocks 16384..) -------
__global__ __launch_bounds__(256) void prep_embed(
    const float* __restrict__ feat, const float* __restrict__ W_emb,
    const float* __restrict__ b_emb, const float* __restrict__ ln0g,
    const float* __restrict__ ln0b, unsigned short* __restrict__ xh,
    const float* __restrict__ Wg, const float* __restrict__ attS,
    const float* __restrict__ attD,
    const float* __restrict__ pW1, const float* __restrict__ pW2,
    const float* __restrict__ vW1, const float* __restrict__ vW2,
    unsigned short* __restrict__ wh, unsigned short* __restrict__ wl,
    unsigned short* __restrict__ w1h, unsigned short* __restrict__ w1l,
    unsigned short* __restrict__ w2h, unsigned short* __restrict__ w2l,
    float* __restrict__ w1t, float* __restrict__ w2t)
{
    if (blockIdx.x < NNODES / 4) {
        // ---- embedding + LN + ReLU -> xh (bf16) ----
        int node = blockIdx.x * 4 + (threadIdx.x >> 6);
        int lane = threadIdx.x & 63;
        float f[10];
#pragma unroll
        for (int i = 0; i < 10; i++) f[i] = feat[node * 10 + i];
        int c0 = 2 * lane, c1 = c0 + 1;
        float v0 = b_emb[c0], v1 = b_emb[c1];
#pragma unroll
        for (int i = 0; i < 10; i++) {
            v0 = fmaf(f[i], W_emb[i * HID + c0], v0);
            v1 = fmaf(f[i], W_emb[i * HID + c1], v1);
        }
        float mu = wave_reduce_sum(v0 + v1) * (1.f / 128.f);
        float e0 = v0 - mu, e1 = v1 - mu;
        float var = wave_reduce_sum(e0 * e0 + e1 * e1) * (1.f / 128.f);
        float r = 1.f / sqrtf(var + 1e-5f);
        float r0 = fmaxf(e0 * r * ln0g[c0] + ln0b[c0], 0.f);
        float r1 = fmaxf(e1 * r * ln0g[c1] + ln0b[c1], 0.f);
        *(unsigned*)(xh + (size_t)node * HID + c0) =
            (unsigned)bf16_rne(r0) | ((unsigned)bf16_rne(r1) << 16);
        return;
    }
    int id = (blockIdx.x - NNODES / 4) * 256 + threadIdx.x;
    if (id < 4 * 144 * 128) {
        int l = id / (144 * 128);
        int rem = id % (144 * 128);
        int n = rem / 128, k = rem % 128;
        const float* W = Wg + (size_t)l * HID * HID;
        float v = 0.f;
        if (n < 128) {
            v = W[k * HID + n];
        } else if (n < 136) {
            int h = (n - 128) & 3;
            const float* av = ((n - 128) < 4 ? attS : attD) + l * HID + h * CHANS;
            for (int c = 0; c < CHANS; c++) v += W[k * HID + h * CHANS + c] * av[c];
        }
        unsigned short hh = bf16_rne(v);
        int t = n >> 4, bcol = n & 15;
        int ks = k >> 5, kq = (k >> 3) & 3, e = k & 7;
        size_t o = (size_t)l * (144 * 128) + (size_t)(((t * 4 + ks) * 64) + (kq * 16 + bcol)) * 8 + e;
        wh[o] = hh;
        wl[o] = bf16_rne(v - bf2f(hh));
        return;
    }
    id -= 4 * 144 * 128;
    if (id < 24576) {
        int n, k;
        float v;
        unsigned short *dh, *dl;
        if (id < 16384) {
            n = id / 128; k = id % 128;
            v = pW1[k * 128 + n];
            dh = w1h; dl = w1l;
        } else {
            int j = id - 16384;
            n = j / 128; k = j % 128;
            v = pW2[k * 64 + n];
            dh = w2h; dl = w2l;
        }
        unsigned short hh = bf16_rne(v);
        int t = n >> 4, bcol = n & 15;
        int ks = k >> 5, kq = (k >> 3) & 3, e = k & 7;
        size_t o = (size_t)(((t * 4 + ks) * 64) + (kq * 16 + bcol)) * 8 + e;
        dh[o] = hh;
        dl[o] = bf16_rne(v - bf2f(hh));
        return;
    }
    id -= 24576;
    if (id < 16384) {
        int t = id >> 7, k = id & 127;
        w1t[t * 128 + k] = vW1[k * 128 + t];
    } else if (id < 24576) {
        int j = id - 16384;
        int t = j >> 7, k = j & 127;
        w2t[t * 128 + k] = vW2[k * 64 + t];
    }
}

// ---------------- MFMA GEMM, K=128, 2-product (Ah*Bh + Ah*Bl) ----
template <int NT, int EPI>
__global__ __launch_bounds__(512, 4) void mfma_gemm(
    const unsigned short* __restrict__ Ah,
    const unsigned short* __restrict__ Bh, const unsigned short* __restrict__ Bl,
    const float* __restrict__ bias,
    unsigned short* __restrict__ outH,
    float* __restrict__ a_s, float* __restrict__ a_d,
    const float* __restrict__ wfin, const float* __restrict__ bfin,
    float* __restrict__ outF)
{
    __shared__ unsigned short lds[NT * 2048];

    int tid = threadIdx.x;
    int wid = tid >> 6, l = tid & 63;
    int row = blockIdx.x * 128 + wid * 16 + (l & 15);
    int kg = (l >> 4) * 8;

    const unsigned short* arh = Ah + (size_t)row * 128 + kg;
    bf16x8 afh[4];
#pragma unroll
    for (int ks = 0; ks < 4; ks++) afh[ks] = *(const bf16x8*)(arh + ks * 32);

    f32x4 acc[NT];
#pragma unroll
    for (int t = 0; t < NT; t++) acc[t] = (f32x4){0.f, 0.f, 0.f, 0.f};

#pragma unroll
    for (int p = 0; p < 2; p++) {
        __syncthreads();   // all waves done reading previous LDS contents
        for (int c = wid; c < 4 * NT; c += 8) {
            int fr = c >> 1, lo = c & 1;
            int t = fr >> 1, ksl = fr & 1;
            const unsigned short* src = (lo ? Bl : Bh)
                + ((size_t)(t * 4 + p * 2 + ksl) << 9) + ((unsigned)l << 3);
            gload_lds16(src, &lds[(size_t)c << 9]);
        }
        __syncthreads();   // drains vmcnt (global_load_lds) before reads
#pragma unroll
        for (int ksl = 0; ksl < 2; ksl++) {
            int ks = p * 2 + ksl;
#pragma unroll
            for (int t = 0; t < NT; t++) {
                const unsigned short* bp = &lds[(((t * 2 + ksl) << 1) << 9) + (l << 3)];
                bf16x8 bh  = *(const bf16x8*)bp;
                bf16x8 blo = *(const bf16x8*)(bp + 512);
                acc[t] = __builtin_amdgcn_mfma_f32_16x16x32_bf16(afh[ks], bh,  acc[t], 0, 0, 0);
                acc[t] = __builtin_amdgcn_mfma_f32_16x16x32_bf16(afh[ks], blo, acc[t], 0, 0, 0);
            }
        }
    }

    // C/D layout: col = lane&15, row = (lane>>4)*4 + reg   [HW-verified]
    int ecol = l & 15;
    int er0 = blockIdx.x * 128 + wid * 16 + ((l >> 4) << 2);

    if constexpr (EPI == 0) {
#pragma unroll
        for (int t = 0; t < 8; t++)
#pragma unroll
            for (int j = 0; j < 4; j++)
                outH[(size_t)(er0 + j) * 128 + t * 16 + ecol] = bf16_rne(acc[t][j]);
#pragma unroll
        for (int j = 0; j < 4; j++) {
            float v = acc[8][j];
            if (ecol < 4)      a_s[(er0 + j) * 4 + ecol] = v;
            else if (ecol < 8) a_d[(er0 + j) * 4 + (ecol - 4)] = v;
        }
    } else if constexpr (EPI == 1) {
#pragma unroll
        for (int t = 0; t < NT; t++)
#pragma unroll
            for (int j = 0; j < 4; j++) {
                float v = fmaxf(acc[t][j] + bias[t * 16 + ecol], 0.f);
                outH[(size_t)(er0 + j) * 128 + t * 16 + ecol] = bf16_rne(v);
            }
    } else {
        float p0[4], p1[4];
#pragma unroll
        for (int j = 0; j < 4; j++) { p0[j] = 0.f; p1[j] = 0.f; }
#pragma unroll
        for (int t = 0; t < NT; t++) {
            int cc = t * 16 + ecol;
            float w0 = wfin[cc * 2 + 0], w1 = wfin[cc * 2 + 1];
#pragma unroll
            for (int j = 0; j < 4; j++) {
                float v = fmaxf(acc[t][j] + bias[cc], 0.f);
                p0[j] = fmaf(v, w0, p0[j]);
                p1[j] = fmaf(v, w1, p1[j]);
            }
        }
#pragma unroll
        for (int m = 1; m < 16; m <<= 1)
#pragma unroll
            for (int j = 0; j < 4; j++) {
                p0[j] += __shfl_xor(p0[j], m, 64);
                p1[j] += __shfl_xor(p1[j], m, 64);
            }
        if (ecol == 0) {
            float b0 = bfin[0], b1 = bfin[1];
#pragma unroll
            for (int j = 0; j < 4; j++) {
                outF[(er0 + j) * 2 + 0] = p0[j] + b0;
                outF[(er0 + j) * 2 + 1] = p1[j] + b1;
            }
        }
    }
}

// ------- fused: softmax (no-max, __expf) + split-wave 4-channel aggregate + epilogue ----
// lanes 0-31 process even edges, lanes 32-63 odd edges; each lane owns 4 channels
// (uint2 load, 8B). Halves merged via shfl_xor(32). 16 edges per batch -> deg<=16
// (most nodes) = one latency exposure.
__global__ __launch_bounds__(256, 4) void gat_agg(
    const unsigned short* __restrict__ hb, const float* __restrict__ a_s,
    const float* __restrict__ a_d, const int* __restrict__ offs,
    const int* __restrict__ col, const float* __restrict__ bgl,
    const float* __restrict__ gl, const float* __restrict__ bl,
    unsigned short* __restrict__ xh)
{
    __shared__ int2 whs[4][4][64];   // [wave][head][edge] = {w_bits, src}
    int wv = threadIdx.x >> 6;
    int lane = threadIdx.x & 63;
    int node = blockIdx.x * 4 + wv;
    int s = offs[node], e = offs[node + 1];
    int deg = e - s;
    float4 ad = *(const float4*)(a_d + (size_t)node * 4);

    int half = lane >> 5;          // 0: even edges, 1: odd edges
    int lq = lane & 31;
    int c0 = 4 * lq;               // this lane's 4 channels
    int head = lq >> 3;            // c0/32
    float acc0 = 0.f, acc1 = 0.f, acc2 = 0.f, acc3 = 0.f;
    float den;

    if (deg <= 64) {
        // score phase: lane-parallel over edges (all 64 lanes; zero-pad beyond deg)
        int src = 0;
        float e0 = 0.f, e1 = 0.f, e2 = 0.f, e3 = 0.f;
        if (lane < deg) {
            src = col[s + lane];
            float4 as = *(const float4*)(a_s + (size_t)src * 4);
            float s0 = as.x + ad.x; s0 = fmaxf(s0, 0.2f * s0);
            float s1 = as.y + ad.y; s1 = fmaxf(s1, 0.2f * s1);
            float s2 = as.z + ad.z; s2 = fmaxf(s2, 0.2f * s2);
            float s3 = as.w + ad.w; s3 = fmaxf(s3, 0.2f * s3);
            e0 = __expf(s0); e1 = __expf(s1); e2 = __expf(s2); e3 = __expf(s3);
        }
        whs[wv][0][lane] = make_int2(__float_as_int(e0), src);
        whs[wv][1][lane] = make_int2(__float_as_int(e1), src);
        whs[wv][2][lane] = make_int2(__float_as_int(e2), src);
        whs[wv][3][lane] = make_int2(__float_as_int(e3), src);
        // same-wave LDS RAW: no barrier. Each half-wave takes every other edge.
        den = (half == 0) ? 1e-16f : 0.f;
        const int2* wrow = &whs[wv][head][0];
        int dg16 = (deg + 15) & ~15;
        for (int j = 0; j < dg16; j += 16) {
            int2 q[8];
#pragma unroll
            for (int u = 0; u < 8; u++) q[u] = wrow[j + 2 * u + half];
            uint2 hv[8];
#pragma unroll
            for (int u = 0; u < 8; u++)
                hv[u] = *(const uint2*)(hb + (((unsigned)q[u].y << 7) + (unsigned)c0));
#pragma unroll
            for (int u = 0; u < 8; u++) {
                float w = __int_as_float(q[u].x);
                den += w;
                acc0 = fmaf(w, __uint_as_float(hv[u].x << 16), acc0);
                acc1 = fmaf(w, __uint_as_float(hv[u].x & 0xffff0000u), acc1);
                acc2 = fmaf(w, __uint_as_float(hv[u].y << 16), acc2);
                acc3 = fmaf(w, __uint_as_float(hv[u].y & 0xffff0000u), acc3);
            }
        }
        // merge even/odd halves (both halves end with full sums)
        acc0 += __shfl_xor(acc0, 32, 64);
        acc1 += __shfl_xor(acc1, 32, 64);
        acc2 += __shfl_xor(acc2, 32, 64);
        acc3 += __shfl_xor(acc3, 32, 64);
        den  += __shfl_xor(den, 32, 64);
    } else {
        // rare fallback: serial over all edges, every lane covers its 4 channels
        den = 1e-16f;
        for (int j = s; j < e; j++) {
            int src = col[j];
            float4 as = *(const float4*)(a_s + (size_t)src * 4);
            float sh = (head == 0) ? (as.x + ad.x) : (head == 1) ? (as.y + ad.y)
                     : (head == 2) ? (as.z + ad.z) : (as.w + ad.w);
            sh = fmaxf(sh, 0.2f * sh);
            float wj = __expf(sh);
            den += wj;
            uint2 hv = *(const uint2*)(hb + (((unsigned)src << 7) + (unsigned)c0));
            acc0 = fmaf(wj, __uint_as_float(hv.x << 16), acc0);
            acc1 = fmaf(wj, __uint_as_float(hv.x & 0xffff0000u), acc1);
            acc2 = fmaf(wj, __uint_as_float(hv.y << 16), acc2);
            acc3 = fmaf(wj, __uint_as_float(hv.y & 0xffff0000u), acc3);
        }
    }
    float inv = 1.f / den;
    acc0 *= inv; acc1 *= inv; acc2 *= inv; acc3 *= inv;

    // epilogue: + bias, ReLU, residual (bf16 x), LayerNorm, write x
    // both halves hold identical channel data -> reduce over 64 lanes counts each
    // channel twice -> scale by 1/256
    float o0 = fmaxf(acc0 + bgl[c0 + 0], 0.f);
    float o1 = fmaxf(acc1 + bgl[c0 + 1], 0.f);
    float o2 = fmaxf(acc2 + bgl[c0 + 2], 0.f);
    float o3 = fmaxf(acc3 + bgl[c0 + 3], 0.f);
    size_t xi = (size_t)node * HID;
    uint2 xv = *(const uint2*)(xh + xi + c0);
    float t0 = __uint_as_float(xv.x << 16) + o0;
    float t1 = __uint_as_float(xv.x & 0xffff0000u) + o1;
    float t2 = __uint_as_float(xv.y << 16) + o2;
    float t3 = __uint_as_float(xv.y & 0xffff0000u) + o3;
    float mu = wave_reduce_sum((t0 + t1) + (t2 + t3)) * (1.f / 256.f);
    float e0 = t0 - mu, e1 = t1 - mu, e2 = t2 - mu, e3 = t3 - mu;
    float var = wave_reduce_sum((e0 * e0 + e1 * e1) + (e2 * e2 + e3 * e3)) * (1.f / 256.f);
    float r = 1.f / sqrtf(var + 1e-5f);
    float r0 = e0 * r * gl[c0 + 0] + bl[c0 + 0];
    float r1 = e1 * r * gl[c0 + 1] + bl[c0 + 1];
    float r2 = e2 * r * gl[c0 + 2] + bl[c0 + 2];
    float r3 = e3 * r * gl[c0 + 3] + bl[c0 + 3];
    if (half == 0) {
        uint2 ov;
        ov.x = (unsigned)bf16_rne(r0) | ((unsigned)bf16_rne(r1) << 16);
        ov.y = (unsigned)bf16_rne(r2) | ((unsigned)bf16_rne(r3) << 16);
        *(uint2*)(xh + xi + c0) = ov;
    }
}

// ---------------- value head ----------------
__global__ void pool_sum(const unsigned short* __restrict__ xh, float* __restrict__ partial) {
    int t = threadIdx.x;
    int base = blockIdx.x * 256;
    float s = 0.f;
    for (int i = 0; i < 256; i++)
        s += bf2f(xh[(size_t)(base + i) * HID + t]);
    partial[blockIdx.x * 128 + t] = s;
}

__global__ void value_mlp(const float* __restrict__ partial,
                          const float* __restrict__ w1t, const float* __restrict__ b1,
                          const float* __restrict__ w2t, const float* __restrict__ b2,
                          const float* __restrict__ W3, const float* __restrict__ b3,
                          float* __restrict__ out)
{
    __shared__ float p[128], h1[128], h2[64];
    int t = threadIdx.x;   // 128
    float s = 0.f;
    for (int i = 0; i < 256; i++) s += partial[i * 128 + t];
    p[t] = s * (1.f / (float)NNODES);
    __syncthreads();
    float a = b1[t];
    const float4* wr = (const float4*)(w1t + (size_t)t * 128);
#pragma unroll
    for (int k4 = 0; k4 < 32; k4++) {
        float4 w = wr[k4];
        a += p[4 * k4] * w.x + p[4 * k4 + 1] * w.y + p[4 * k4 + 2] * w.z + p[4 * k4 + 3] * w.w;
    }
    h1[t] = fmaxf(a, 0.f);
    __syncthreads();
    if (t < 64) {
        float a2 = b2[t];
        const float4* wr2 = (const float4*)(w2t + (size_t)t * 128);
#pragma unroll
        for (int k4 = 0; k4 < 32; k4++) {
            float4 w = wr2[k4];
            a2 += h1[4 * k4] * w.x + h1[4 * k4 + 1] * w.y + h1[4 * k4 + 2] * w.z + h1[4 * k4 + 3] * w.w;
        }
        h2[t] = fmaxf(a2, 0.f);
    }
    __syncthreads();
    if (t == 0) {
        float v = b3[0];
        for (int k = 0; k < 64; k++) v = fmaf(h2[k], W3[k], v);
        out[NDATA * 2] = v;
    }
}

extern "C" void kernel_launch(void* const* d_in, const int* in_sizes, int n_in,
                              void* d_out, int out_size, void* d_ws, size_t ws_size,
                              hipStream_t stream)
{
    const float* feat  = (const float*)d_in[0];
    const int*   ei    = (const int*)d_in[1];
    const float* W_emb = (const float*)d_in[2];
    const float* b_emb = (const float*)d_in[3];
    const float* ln0g  = (const float*)d_in[4];
    const float* ln0b  = (const float*)d_in[5];
    const float* Wg    = (const float*)d_in[6];
    const float* att_s = (const float*)d_in[7];
    const float* att_d = (const float*)d_in[8];
    const float* bg    = (const float*)d_in[9];
    const float* lng   = (const float*)d_in[10];
    const float* lnb   = (const float*)d_in[11];
    const float* pW1 = (const float*)d_in[12]; const float* pb1 = (const float*)d_in[13];
    const float* pW2 = (const float*)d_in[14]; const float* pb2 = (const float*)d_in[15];
    const float* pW3 = (const float*)d_in[16]; const float* pb3 = (const float*)d_in[17];
    const float* vW1 = (const float*)d_in[18]; const float* vb1 = (const float*)d_in[19];
    const float* vW2 = (const float*)d_in[20]; const float* vb2 = (const float*)d_in[21];
    const float* vW3 = (const float*)d_in[22]; const float* vb3 = (const float*)d_in[23];
    float* out = (float*)d_out;
    int Eo = in_sizes[1] / 2;

    // workspace layout
    unsigned short* xh = (unsigned short*)d_ws;              // 65536*128 bf16
    unsigned short* hb = xh + (size_t)NNODES * HID;          // h bf16; reused as ph1h
    float* a_s = (float*)(hb + (size_t)NNODES * HID);
    float* a_d = a_s + NNODES * HEADS;
    unsigned short* wgt_h = (unsigned short*)(a_d + NNODES * HEADS);  // 4*144*128
    unsigned short* wgt_l = wgt_h + 4 * 144 * 128;
    unsigned short* pw1h  = wgt_l + 4 * 144 * 128;           // 128*128
    unsigned short* pw1l  = pw1h + 128 * 128;
    unsigned short* pw2h  = pw1l + 128 * 128;                // 64*128
    unsigned short* pw2l  = pw2h + 64 * 128;
    float* w1t  = (float*)(pw2l + 64 * 128);                 // 128*128 f32
    float* w2t  = w1t + 128 * 128;                           // 64*128 f32
    float* partial = w2t + 64 * 128;                         // 256*128 f32
    int* deg    = (int*)(partial + 256 * 128);
    int* offs   = deg + NNODES;
    int* cursor = offs + NNODES + 2;
    int* bsum   = cursor + NNODES;
    int* col    = bsum + 256;
    unsigned short* ph1h = hb;

    // merged embedding + weight prep (embed blocks first, then 480 prep blocks)
    prep_embed<<<NNODES / 4 + 480, 256, 0, stream>>>(
        feat, W_emb, b_emb, ln0g, ln0b, xh,
        Wg, att_s, att_d, pW1, pW2, vW1, vW2,
        wgt_h, wgt_l, pw1h, pw1l, pw2h, pw2l, w1t, w2t);

    // CSR build (dst -> src list), self-loops included (+1 folded into scan1)
    hipMemsetAsync(deg, 0, (size_t)NNODES * 4, stream);
    hist_kernel<<<(Eo + 255) / 256, 256, 0, stream>>>(ei, deg, Eo);
    scan1<<<256, 256, 0, stream>>>(deg, offs, bsum);
    scan3<<<256, 256, 0, stream>>>(offs, bsum, cursor, Eo);
    fill_kernel<<<(Eo + NNODES + 255) / 256, 256, 0, stream>>>(ei, cursor, col, Eo);

    // GAT layers
    for (int l = 0; l < LAYERS; l++) {
        mfma_gemm<9, 0><<<NNODES / 128, 512, 0, stream>>>(
            xh, wgt_h + (size_t)l * 144 * 128, wgt_l + (size_t)l * 144 * 128,
            nullptr, hb, a_s, a_d, nullptr, nullptr, nullptr);
        gat_agg<<<NNODES / 4, 256, 0, stream>>>(
            hb, a_s, a_d, offs, col, bg + l * HID, lng + l * HID, lnb + l * HID, xh);
    }

    // policy head: GEMM1 -> bf16-hi ph1; GEMM2 + fused [64,2] -> logits
    mfma_gemm<8, 1><<<NDATA / 128, 512, 0, stream>>>(
        xh, pw1h, pw1l, pb1, ph1h, nullptr, nullptr, nullptr, nullptr, nullptr);
    mfma_gemm<4, 2><<<NDATA / 128, 512, 0, stream>>>(
        ph1h, pw2h, pw2l, pb2, nullptr, nullptr, nullptr, pW3, pb3, out);

    // value head
    pool_sum<<<256, 128, 0, stream>>>(xh, partial);
    value_mlp<<<1, 128, 0, stream>>>(partial, w1t, vb1, w2t, vb2, vW3, vb3, out);
}

// Round 14
// 322.233 us; speedup vs baseline: 1.0291x; 1.0291x over previous
//
#include <hip/hip_runtime.h>

#define NNODES 65536
#define NDATA  32768
#define HID    128
#define HEADS  4
#define CHANS  32
#define LAYERS 4

using bf16x8 = __attribute__((ext_vector_type(8))) short;
using f32x4  = __attribute__((ext_vector_type(4))) float;

__device__ __forceinline__ float wave_reduce_sum(float v) {
#pragma unroll
    for (int m = 1; m < 64; m <<= 1) v += __shfl_xor(v, m, 64);
    return v;
}

__device__ __forceinline__ int wave_reduce_sum_i(int v) {
#pragma unroll
    for (int m = 1; m < 64; m <<= 1) v += __shfl_xor(v, m, 64);
    return v;
}

__device__ __forceinline__ unsigned short bf16_rne(float f) {
    unsigned u = __float_as_uint(f);
    return (unsigned short)((u + 0x7fffu + ((u >> 16) & 1u)) >> 16);
}
__device__ __forceinline__ float bf2f(unsigned short u) {
    return __uint_as_float((unsigned)u << 16);
}

__device__ __forceinline__ void gload_lds16(const unsigned short* g, unsigned short* l) {
    __builtin_amdgcn_global_load_lds(
        (const __attribute__((address_space(1))) void*)g,
        (__attribute__((address_space(3))) void*)l, 16, 0, 0);
}

// ---------------- CSR build ----------------
__global__ void hist_kernel(const int* __restrict__ ei, int* __restrict__ deg, int Eo) {
    int e = blockIdx.x * 256 + threadIdx.x;
    if (e >= Eo) return;
    atomicAdd(&deg[ei[Eo + e]], 1);   // dst row
}

// reads deg+1 (self-loop folded here; deg zeroed by memset)
__global__ void scan1(const int* __restrict__ deg, int* __restrict__ offs, int* __restrict__ bsum) {
    __shared__ int s[256];
    int t = threadIdx.x, b = blockIdx.x;
    int v = deg[b * 256 + t] + 1;
    s[t] = v;
    __syncthreads();
    for (int off = 1; off < 256; off <<= 1) {
        int add = (t >= off) ? s[t - off] : 0;
        __syncthreads();
        s[t] += add;
        __syncthreads();
    }
    offs[b * 256 + t] = s[t] - v;
    if (t == 255) bsum[b] = s[255];
}

// scan2 folded in: block b reduces bsum[0..b-1] itself (256 threads, masked)
__global__ void scan3(int* __restrict__ offs, const int* __restrict__ bsum,
                      int* __restrict__ cursor, int Eo) {
    __shared__ int ws[4];
    int b = blockIdx.x, t = threadIdx.x;
    int v = (t < b) ? bsum[t] : 0;
    v = wave_reduce_sum_i(v);
    if ((t & 63) == 0) ws[t >> 6] = v;
    __syncthreads();
    int base = ws[0] + ws[1] + ws[2] + ws[3];
    int i = b * 256 + t;
    int o = offs[i] + base;
    offs[i] = o;
    cursor[i] = o;
    if (i == 0) offs[NNODES] = Eo + NNODES;
}

__global__ void fill_kernel(const int* __restrict__ ei, int* __restrict__ cursor,
                            int* __restrict__ col, int Eo) {
    int e = blockIdx.x * 256 + threadIdx.x;
    int Etot = Eo + NNODES;
    if (e >= Etot) return;
    int src, dst;
    if (e < Eo) { src = ei[e]; dst = ei[Eo + e]; }
    else        { src = dst = e - Eo; }
    int pos = atomicAdd(&cursor[dst], 1);
    col[pos] = src;
}

// ------- merged: embedding (blocks 0..16383) + all weight prep (blocks 16384..) -------
__global__ __launch_bounds__(256) void prep_embed(
    const float* __restrict__ feat, const float* __restrict__ W_emb,
    const float* __restrict__ b_emb, const float* __restrict__ ln0g,
    const float* __restrict__ ln0b, unsigned short* __restrict__ xh,
    const float* __restrict__ Wg, const float* __restrict__ attS,
    const float* __restrict__ attD,
    const float* __restrict__ pW1, const float* __restrict__ pW2,
    const float* __restrict__ vW1, const float* __restrict__ vW2,
    unsigned short* __restrict__ wh, unsigned short* __restrict__ wl,
    unsigned short* __restrict__ w1h, unsigned short* __restrict__ w1l,
    unsigned short* __restrict__ w2h, unsigned short* __restrict__ w2l,
    float* __restrict__ w1t, float* __restrict__ w2t)
{
    if (blockIdx.x < NNODES / 4) {
        // ---- embedding + LN + ReLU -> xh (bf16) ----
        int node = blockIdx.x * 4 + (threadIdx.x >> 6);
        int lane = threadIdx.x & 63;
        float f[10];
#pragma unroll
        for (int i = 0; i < 10; i++) f[i] = feat[node * 10 + i];
        int c0 = 2 * lane, c1 = c0 + 1;
        float v0 = b_emb[c0], v1 = b_emb[c1];
#pragma unroll
        for (int i = 0; i < 10; i++) {
            v0 = fmaf(f[i], W_emb[i * HID + c0], v0);
            v1 = fmaf(f[i], W_emb[i * HID + c1], v1);
        }
        float mu = wave_reduce_sum(v0 + v1) * (1.f / 128.f);
        float e0 = v0 - mu, e1 = v1 - mu;
        float var = wave_reduce_sum(e0 * e0 + e1 * e1) * (1.f / 128.f);
        float r = 1.f / sqrtf(var + 1e-5f);
        float r0 = fmaxf(e0 * r * ln0g[c0] + ln0b[c0], 0.f);
        float r1 = fmaxf(e1 * r * ln0g[c1] + ln0b[c1], 0.f);
        *(unsigned*)(xh + (size_t)node * HID + c0) =
            (unsigned)bf16_rne(r0) | ((unsigned)bf16_rne(r1) << 16);
        return;
    }
    int id = (blockIdx.x - NNODES / 4) * 256 + threadIdx.x;
    if (id < 4 * 144 * 128) {
        int l = id / (144 * 128);
        int rem = id % (144 * 128);
        int n = rem / 128, k = rem % 128;
        const float* W = Wg + (size_t)l * HID * HID;
        float v = 0.f;
        if (n < 128) {
            v = W[k * HID + n];
        } else if (n < 136) {
            int h = (n - 128) & 3;
            const float* av = ((n - 128) < 4 ? attS : attD) + l * HID + h * CHANS;
            for (int c = 0; c < CHANS; c++) v += W[k * HID + h * CHANS + c] * av[c];
        }
        unsigned short hh = bf16_rne(v);
        int t = n >> 4, bcol = n & 15;
        int ks = k >> 5, kq = (k >> 3) & 3, e = k & 7;
        size_t o = (size_t)l * (144 * 128) + (size_t)(((t * 4 + ks) * 64) + (kq * 16 + bcol)) * 8 + e;
        wh[o] = hh;
        wl[o] = bf16_rne(v - bf2f(hh));
        return;
    }
    id -= 4 * 144 * 128;
    if (id < 24576) {
        int n, k;
        float v;
        unsigned short *dh, *dl;
        if (id < 16384) {
            n = id / 128; k = id % 128;
            v = pW1[k * 128 + n];
            dh = w1h; dl = w1l;
        } else {
            int j = id - 16384;
            n = j / 128; k = j % 128;
            v = pW2[k * 64 + n];
            dh = w2h; dl = w2l;
        }
        unsigned short hh = bf16_rne(v);
        int t = n >> 4, bcol = n & 15;
        int ks = k >> 5, kq = (k >> 3) & 3, e = k & 7;
        size_t o = (size_t)(((t * 4 + ks) * 64) + (kq * 16 + bcol)) * 8 + e;
        dh[o] = hh;
        dl[o] = bf16_rne(v - bf2f(hh));
        return;
    }
    id -= 24576;
    if (id < 16384) {
        int t = id >> 7, k = id & 127;
        w1t[t * 128 + k] = vW1[k * 128 + t];
    } else if (id < 24576) {
        int j = id - 16384;
        int t = j >> 7, k = j & 127;
        w2t[t * 128 + k] = vW2[k * 64 + t];
    }
}

// ---------------- MFMA GEMM, K=128, 2-product (Ah*Bh + Ah*Bl) ----
template <int NT, int EPI>
__global__ __launch_bounds__(512, 4) void mfma_gemm(
    const unsigned short* __restrict__ Ah,
    const unsigned short* __restrict__ Bh, const unsigned short* __restrict__ Bl,
    const float* __restrict__ bias,
    unsigned short* __restrict__ outH,
    float* __restrict__ a_s, float* __restrict__ a_d,
    const float* __restrict__ wfin, const float* __restrict__ bfin,
    float* __restrict__ outF)
{
    __shared__ unsigned short lds[NT * 2048];

    int tid = threadIdx.x;
    int wid = tid >> 6, l = tid & 63;
    int row = blockIdx.x * 128 + wid * 16 + (l & 15);
    int kg = (l >> 4) * 8;

    const unsigned short* arh = Ah + (size_t)row * 128 + kg;
    bf16x8 afh[4];
#pragma unroll
    for (int ks = 0; ks < 4; ks++) afh[ks] = *(const bf16x8*)(arh + ks * 32);

    f32x4 acc[NT];
#pragma unroll
    for (int t = 0; t < NT; t++) acc[t] = (f32x4){0.f, 0.f, 0.f, 0.f};

#pragma unroll
    for (int p = 0; p < 2; p++) {
        __syncthreads();   // all waves done reading previous LDS contents
        for (int c = wid; c < 4 * NT; c += 8) {
            int fr = c >> 1, lo = c & 1;
            int t = fr >> 1, ksl = fr & 1;
            const unsigned short* src = (lo ? Bl : Bh)
                + ((size_t)(t * 4 + p * 2 + ksl) << 9) + ((unsigned)l << 3);
            gload_lds16(src, &lds[(size_t)c << 9]);
        }
        __syncthreads();   // drains vmcnt (global_load_lds) before reads
#pragma unroll
        for (int ksl = 0; ksl < 2; ksl++) {
            int ks = p * 2 + ksl;
#pragma unroll
            for (int t = 0; t < NT; t++) {
                const unsigned short* bp = &lds[(((t * 2 + ksl) << 1) << 9) + (l << 3)];
                bf16x8 bh  = *(const bf16x8*)bp;
                bf16x8 blo = *(const bf16x8*)(bp + 512);
                acc[t] = __builtin_amdgcn_mfma_f32_16x16x32_bf16(afh[ks], bh,  acc[t], 0, 0, 0);
                acc[t] = __builtin_amdgcn_mfma_f32_16x16x32_bf16(afh[ks], blo, acc[t], 0, 0, 0);
            }
        }
    }

    // C/D layout: col = lane&15, row = (lane>>4)*4 + reg   [HW-verified]
    int ecol = l & 15;
    int er0 = blockIdx.x * 128 + wid * 16 + ((l >> 4) << 2);

    if constexpr (EPI == 0) {
#pragma unroll
        for (int t = 0; t < 8; t++)
#pragma unroll
            for (int j = 0; j < 4; j++)
                outH[(size_t)(er0 + j) * 128 + t * 16 + ecol] = bf16_rne(acc[t][j]);
#pragma unroll
        for (int j = 0; j < 4; j++) {
            float v = acc[8][j];
            if (ecol < 4)      a_s[(er0 + j) * 4 + ecol] = v;
            else if (ecol < 8) a_d[(er0 + j) * 4 + (ecol - 4)] = v;
        }
    } else if constexpr (EPI == 1) {
#pragma unroll
        for (int t = 0; t < NT; t++)
#pragma unroll
            for (int j = 0; j < 4; j++) {
                float v = fmaxf(acc[t][j] + bias[t * 16 + ecol], 0.f);
                outH[(size_t)(er0 + j) * 128 + t * 16 + ecol] = bf16_rne(v);
            }
    } else {
        float p0[4], p1[4];
#pragma unroll
        for (int j = 0; j < 4; j++) { p0[j] = 0.f; p1[j] = 0.f; }
#pragma unroll
        for (int t = 0; t < NT; t++) {
            int cc = t * 16 + ecol;
            float w0 = wfin[cc * 2 + 0], w1 = wfin[cc * 2 + 1];
#pragma unroll
            for (int j = 0; j < 4; j++) {
                float v = fmaxf(acc[t][j] + bias[cc], 0.f);
                p0[j] = fmaf(v, w0, p0[j]);
                p1[j] = fmaf(v, w1, p1[j]);
            }
        }
#pragma unroll
        for (int m = 1; m < 16; m <<= 1)
#pragma unroll
            for (int j = 0; j < 4; j++) {
                p0[j] += __shfl_xor(p0[j], m, 64);
                p1[j] += __shfl_xor(p1[j], m, 64);
            }
        if (ecol == 0) {
            float b0 = bfin[0], b1 = bfin[1];
#pragma unroll
            for (int j = 0; j < 4; j++) {
                outF[(er0 + j) * 2 + 0] = p0[j] + b0;
                outF[(er0 + j) * 2 + 1] = p1[j] + b1;
            }
        }
    }
}

// ------- fused: per-dst softmax (no-max, __expf) + 8-wide ILP aggregate + epilogue ----
// R12 structure (best measured); launch_bounds raised to 8 waves/EU for occupancy.
__global__ __launch_bounds__(256, 8) void gat_agg(
    const unsigned short* __restrict__ hb, const float* __restrict__ a_s,
    const float* __restrict__ a_d, const int* __restrict__ offs,
    const int* __restrict__ col, const float* __restrict__ bgl,
    const float* __restrict__ gl, const float* __restrict__ bl,
    unsigned short* __restrict__ xh)
{
    __shared__ int2 whs[4][4][64];   // [wave][head][edge] = {w_bits, src}
    int wv = threadIdx.x >> 6;
    int lane = threadIdx.x & 63;
    int node = blockIdx.x * 4 + wv;
    int s = offs[node], e = offs[node + 1];
    int deg = e - s;
    float4 ad = *(const float4*)(a_d + (size_t)node * 4);

    int c0 = 2 * lane, c1 = 2 * lane + 1;
    int head = lane >> 4;
    float acc0 = 0.f, acc1 = 0.f;
    float den = 1e-16f;

    if (deg <= 64) {
        int src = 0;
        float e0 = 0.f, e1 = 0.f, e2 = 0.f, e3 = 0.f;
        if (lane < deg) {
            src = col[s + lane];
            float4 as = *(const float4*)(a_s + (size_t)src * 4);
            float s0 = as.x + ad.x; s0 = fmaxf(s0, 0.2f * s0);
            float s1 = as.y + ad.y; s1 = fmaxf(s1, 0.2f * s1);
            float s2 = as.z + ad.z; s2 = fmaxf(s2, 0.2f * s2);
            float s3 = as.w + ad.w; s3 = fmaxf(s3, 0.2f * s3);
            e0 = __expf(s0); e1 = __expf(s1); e2 = __expf(s2); e3 = __expf(s3);
        }
        whs[wv][0][lane] = make_int2(__float_as_int(e0), src);
        whs[wv][1][lane] = make_int2(__float_as_int(e1), src);
        whs[wv][2][lane] = make_int2(__float_as_int(e2), src);
        whs[wv][3][lane] = make_int2(__float_as_int(e3), src);
        // same-wave LDS RAW: no barrier needed. 8-wide batch: 8 independent gathers
        // in flight per wave -> 1-2 latency exposures per node (Poisson(9) degree).
        const int2* wrow = &whs[wv][head][0];
        int dg8 = (deg + 7) & ~7;
        for (int j = 0; j < dg8; j += 8) {
            int2 q[8];
#pragma unroll
            for (int u = 0; u < 8; u++) q[u] = wrow[j + u];
            unsigned hv[8];
#pragma unroll
            for (int u = 0; u < 8; u++)
                hv[u] = *(const unsigned*)(hb + (((unsigned)q[u].y << 7) + (unsigned)c0));
#pragma unroll
            for (int u = 0; u < 8; u++) {
                float w = __int_as_float(q[u].x);
                den += w;
                acc0 = fmaf(w, __uint_as_float(hv[u] << 16), acc0);
                acc1 = fmaf(w, __uint_as_float(hv[u] & 0xffff0000u), acc1);
            }
        }
    } else {
        for (int j = s; j < e; j++) {
            int src = col[j];
            float4 as = *(const float4*)(a_s + (size_t)src * 4);
            float sh = (head == 0) ? (as.x + ad.x) : (head == 1) ? (as.y + ad.y)
                     : (head == 2) ? (as.z + ad.z) : (as.w + ad.w);
            sh = fmaxf(sh, 0.2f * sh);
            float wj = __expf(sh);
            den += wj;
            unsigned hv = *(const unsigned*)(hb + (((unsigned)src << 7) + (unsigned)c0));
            acc0 = fmaf(wj, __uint_as_float(hv << 16), acc0);
            acc1 = fmaf(wj, __uint_as_float(hv & 0xffff0000u), acc1);
        }
    }
    float inv = 1.f / den;
    acc0 *= inv;
    acc1 *= inv;

    // epilogue: + bias, ReLU, residual (bf16 x), LayerNorm, write x
    float o0 = fmaxf(acc0 + bgl[c0], 0.f);
    float o1 = fmaxf(acc1 + bgl[c1], 0.f);
    size_t xi = (size_t)node * HID;
    unsigned ph = *(const unsigned*)(xh + xi + c0);
    float t0 = __uint_as_float(ph << 16) + o0;
    float t1 = __uint_as_float(ph & 0xffff0000u) + o1;
    float mu = wave_reduce_sum(t0 + t1) * (1.f / 128.f);
    float e0 = t0 - mu, e1 = t1 - mu;
    float var = wave_reduce_sum(e0 * e0 + e1 * e1) * (1.f / 128.f);
    float r = 1.f / sqrtf(var + 1e-5f);
    float r0 = e0 * r * gl[c0] + bl[c0];
    float r1 = e1 * r * gl[c1] + bl[c1];
    *(unsigned*)(xh + xi + c0) = (unsigned)bf16_rne(r0) | ((unsigned)bf16_rne(r1) << 16);
}

// ---------------- value head ----------------
__global__ void pool_sum(const unsigned short* __restrict__ xh, float* __restrict__ partial) {
    int t = threadIdx.x;
    int base = blockIdx.x * 256;
    float s = 0.f;
    for (int i = 0; i < 256; i++)
        s += bf2f(xh[(size_t)(base + i) * HID + t]);
    partial[blockIdx.x * 128 + t] = s;
}

__global__ void value_mlp(const float* __restrict__ partial,
                          const float* __restrict__ w1t, const float* __restrict__ b1,
                          const float* __restrict__ w2t, const float* __restrict__ b2,
                          const float* __restrict__ W3, const float* __restrict__ b3,
                          float* __restrict__ out)
{
    __shared__ float p[128], h1[128], h2[64];
    int t = threadIdx.x;   // 128
    float s = 0.f;
    for (int i = 0; i < 256; i++) s += partial[i * 128 + t];
    p[t] = s * (1.f / (float)NNODES);
    __syncthreads();
    float a = b1[t];
    const float4* wr = (const float4*)(w1t + (size_t)t * 128);
#pragma unroll
    for (int k4 = 0; k4 < 32; k4++) {
        float4 w = wr[k4];
        a += p[4 * k4] * w.x + p[4 * k4 + 1] * w.y + p[4 * k4 + 2] * w.z + p[4 * k4 + 3] * w.w;
    }
    h1[t] = fmaxf(a, 0.f);
    __syncthreads();
    if (t < 64) {
        float a2 = b2[t];
        const float4* wr2 = (const float4*)(w2t + (size_t)t * 128);
#pragma unroll
        for (int k4 = 0; k4 < 32; k4++) {
            float4 w = wr2[k4];
            a2 += h1[4 * k4] * w.x + h1[4 * k4 + 1] * w.y + h1[4 * k4 + 2] * w.z + h1[4 * k4 + 3] * w.w;
        }
        h2[t] = fmaxf(a2, 0.f);
    }
    __syncthreads();
    if (t == 0) {
        float v = b3[0];
        for (int k = 0; k < 64; k++) v = fmaf(h2[k], W3[k], v);
        out[NDATA * 2] = v;
    }
}

extern "C" void kernel_launch(void* const* d_in, const int* in_sizes, int n_in,
                              void* d_out, int out_size, void* d_ws, size_t ws_size,
                              hipStream_t stream)
{
    const float* feat  = (const float*)d_in[0];
    const int*   ei    = (const int*)d_in[1];
    const float* W_emb = (const float*)d_in[2];
    const float* b_emb = (const float*)d_in[3];
    const float* ln0g  = (const float*)d_in[4];
    const float* ln0b  = (const float*)d_in[5];
    const float* Wg    = (const float*)d_in[6];
    const float* att_s = (const float*)d_in[7];
    const float* att_d = (const float*)d_in[8];
    const float* bg    = (const float*)d_in[9];
    const float* lng   = (const float*)d_in[10];
    const float* lnb   = (const float*)d_in[11];
    const float* pW1 = (const float*)d_in[12]; const float* pb1 = (const float*)d_in[13];
    const float* pW2 = (const float*)d_in[14]; const float* pb2 = (const float*)d_in[15];
    const float* pW3 = (const float*)d_in[16]; const float* pb3 = (const float*)d_in[17];
    const float* vW1 = (const float*)d_in[18]; const float* vb1 = (const float*)d_in[19];
    const float* vW2 = (const float*)d_in[20]; const float* vb2 = (const float*)d_in[21];
    const float* vW3 = (const float*)d_in[22]; const float* vb3 = (const float*)d_in[23];
    float* out = (float*)d_out;
    int Eo = in_sizes[1] / 2;

    // workspace layout
    unsigned short* xh = (unsigned short*)d_ws;              // 65536*128 bf16
    unsigned short* hb = xh + (size_t)NNODES * HID;          // h bf16; reused as ph1h
    float* a_s = (float*)(hb + (size_t)NNODES * HID);
    float* a_d = a_s + NNODES * HEADS;
    unsigned short* wgt_h = (unsigned short*)(a_d + NNODES * HEADS);  // 4*144*128
    unsigned short* wgt_l = wgt_h + 4 * 144 * 128;
    unsigned short* pw1h  = wgt_l + 4 * 144 * 128;           // 128*128
    unsigned short* pw1l  = pw1h + 128 * 128;
    unsigned short* pw2h  = pw1l + 128 * 128;                // 64*128
    unsigned short* pw2l  = pw2h + 64 * 128;
    float* w1t  = (float*)(pw2l + 64 * 128);                 // 128*128 f32
    float* w2t  = w1t + 128 * 128;                           // 64*128 f32
    float* partial = w2t + 64 * 128;                         // 256*128 f32
    int* deg    = (int*)(partial + 256 * 128);
    int* offs   = deg + NNODES;
    int* cursor = offs + NNODES + 2;
    int* bsum   = cursor + NNODES;
    int* col    = bsum + 256;
    unsigned short* ph1h = hb;

    // merged embedding + weight prep (embed blocks first, then 480 prep blocks)
    prep_embed<<<NNODES / 4 + 480, 256, 0, stream>>>(
        feat, W_emb, b_emb, ln0g, ln0b, xh,
        Wg, att_s, att_d, pW1, pW2, vW1, vW2,
        wgt_h, wgt_l, pw1h, pw1l, pw2h, pw2l, w1t, w2t);

    // CSR build (dst -> src list), self-loops included (+1 folded into scan1)
    hipMemsetAsync(deg, 0, (size_t)NNODES * 4, stream);
    hist_kernel<<<(Eo + 255) / 256, 256, 0, stream>>>(ei, deg, Eo);
    scan1<<<256, 256, 0, stream>>>(deg, offs, bsum);
    scan3<<<256, 256, 0, stream>>>(offs, bsum, cursor, Eo);
    fill_kernel<<<(Eo + NNODES + 255) / 256, 256, 0, stream>>>(ei, cursor, col, Eo);

    // GAT layers
    for (int l = 0; l < LAYERS; l++) {
        mfma_gemm<9, 0><<<NNODES / 128, 512, 0, stream>>>(
            xh, wgt_h + (size_t)l * 144 * 128, wgt_l + (size_t)l * 144 * 128,
            nullptr, hb, a_s, a_d, nullptr, nullptr, nullptr);
        gat_agg<<<NNODES / 4, 256, 0, stream>>>(
            hb, a_s, a_d, offs, col, bg + l * HID, lng + l * HID, lnb + l * HID, xh);
    }

    // policy head: GEMM1 -> bf16-hi ph1; GEMM2 + fused [64,2] -> logits
    mfma_gemm<8, 1><<<NDATA / 128, 512, 0, stream>>>(
        xh, pw1h, pw1l, pb1, ph1h, nullptr, nullptr, nullptr, nullptr, nullptr);
    mfma_gemm<4, 2><<<NDATA / 128, 512, 0, stream>>>(
        ph1h, pw2h, pw2l, pb2, nullptr, nullptr, nullptr, pW3, pb3, out);

    // value head
    pool_sum<<<256, 128, 0, stream>>>(xh, partial);
    value_mlp<<<1, 128, 0, stream>>>(partial, w1t, vb1, w2t, vb2, vW3, vb3, out);
}

// Round 15
// 317.293 us; speedup vs baseline: 1.0451x; 1.0156x over previous
//
#include <hip/hip_runtime.h>

#define NNODES 65536
#define NDATA  32768
#define HID    128
#define HEADS  4
#define CHANS  32
#define LAYERS 4

using bf16x8 = __attribute__((ext_vector_type(8))) short;
using f32x4  = __attribute__((ext_vector_type(4))) float;

__device__ __forceinline__ float wave_reduce_sum(float v) {
#pragma unroll
    for (int m = 1; m < 64; m <<= 1) v += __shfl_xor(v, m, 64);
    return v;
}

__device__ __forceinline__ int wave_reduce_sum_i(int v) {
#pragma unroll
    for (int m = 1; m < 64; m <<= 1) v += __shfl_xor(v, m, 64);
    return v;
}

__device__ __forceinline__ unsigned short bf16_rne(float f) {
    unsigned u = __float_as_uint(f);
    return (unsigned short)((u + 0x7fffu + ((u >> 16) & 1u)) >> 16);
}
__device__ __forceinline__ float bf2f(unsigned short u) {
    return __uint_as_float((unsigned)u << 16);
}

__device__ __forceinline__ void gload_lds16(const unsigned short* g, unsigned short* l) {
    __builtin_amdgcn_global_load_lds(
        (const __attribute__((address_space(1))) void*)g,
        (__attribute__((address_space(3))) void*)l, 16, 0, 0);
}

// ---------------- CSR build ----------------
__global__ void hist_kernel(const int* __restrict__ ei, int* __restrict__ deg, int Eo) {
    int e = blockIdx.x * 256 + threadIdx.x;
    if (e >= Eo) return;
    atomicAdd(&deg[ei[Eo + e]], 1);   // dst row
}

// reads deg+1 (self-loop folded here; deg zeroed by memset)
__global__ void scan1(const int* __restrict__ deg, int* __restrict__ offs, int* __restrict__ bsum) {
    __shared__ int s[256];
    int t = threadIdx.x, b = blockIdx.x;
    int v = deg[b * 256 + t] + 1;
    s[t] = v;
    __syncthreads();
    for (int off = 1; off < 256; off <<= 1) {
        int add = (t >= off) ? s[t - off] : 0;
        __syncthreads();
        s[t] += add;
        __syncthreads();
    }
    offs[b * 256 + t] = s[t] - v;
    if (t == 255) bsum[b] = s[255];
}

// scan2 folded in: block b reduces bsum[0..b-1] itself (256 threads, masked)
__global__ void scan3(int* __restrict__ offs, const int* __restrict__ bsum,
                      int* __restrict__ cursor, int Eo) {
    __shared__ int ws[4];
    int b = blockIdx.x, t = threadIdx.x;
    int v = (t < b) ? bsum[t] : 0;
    v = wave_reduce_sum_i(v);
    if ((t & 63) == 0) ws[t >> 6] = v;
    __syncthreads();
    int base = ws[0] + ws[1] + ws[2] + ws[3];
    int i = b * 256 + t;
    int o = offs[i] + base;
    offs[i] = o;
    cursor[i] = o;
    if (i == 0) offs[NNODES] = Eo + NNODES;
}

__global__ void fill_kernel(const int* __restrict__ ei, int* __restrict__ cursor,
                            int* __restrict__ col, int Eo) {
    int e = blockIdx.x * 256 + threadIdx.x;
    int Etot = Eo + NNODES;
    if (e >= Etot) return;
    int src, dst;
    if (e < Eo) { src = ei[e]; dst = ei[Eo + e]; }
    else        { src = dst = e - Eo; }
    int pos = atomicAdd(&cursor[dst], 1);
    col[pos] = src;
}

// ------- merged: embedding (blocks 0..16383) + all weight prep (blocks 16384..) -------
__global__ __launch_bounds__(256) void prep_embed(
    const float* __restrict__ feat, const float* __restrict__ W_emb,
    const float* __restrict__ b_emb, const float* __restrict__ ln0g,
    const float* __restrict__ ln0b, unsigned short* __restrict__ xh,
    const float* __restrict__ Wg, const float* __restrict__ attS,
    const float* __restrict__ attD,
    const float* __restrict__ pW1, const float* __restrict__ pW2,
    const float* __restrict__ vW1, const float* __restrict__ vW2,
    unsigned short* __restrict__ wh, unsigned short* __restrict__ wl,
    unsigned short* __restrict__ w1h, unsigned short* __restrict__ w1l,
    unsigned short* __restrict__ w2h, unsigned short* __restrict__ w2l,
    float* __restrict__ w1t, float* __restrict__ w2t)
{
    if (blockIdx.x < NNODES / 4) {
        // ---- embedding + LN + ReLU -> xh (bf16) ----
        int node = blockIdx.x * 4 + (threadIdx.x >> 6);
        int lane = threadIdx.x & 63;
        float f[10];
#pragma unroll
        for (int i = 0; i < 10; i++) f[i] = feat[node * 10 + i];
        int c0 = 2 * lane, c1 = c0 + 1;
        float v0 = b_emb[c0], v1 = b_emb[c1];
#pragma unroll
        for (int i = 0; i < 10; i++) {
            v0 = fmaf(f[i], W_emb[i * HID + c0], v0);
            v1 = fmaf(f[i], W_emb[i * HID + c1], v1);
        }
        float mu = wave_reduce_sum(v0 + v1) * (1.f / 128.f);
        float e0 = v0 - mu, e1 = v1 - mu;
        float var = wave_reduce_sum(e0 * e0 + e1 * e1) * (1.f / 128.f);
        float r = 1.f / sqrtf(var + 1e-5f);
        float r0 = fmaxf(e0 * r * ln0g[c0] + ln0b[c0], 0.f);
        float r1 = fmaxf(e1 * r * ln0g[c1] + ln0b[c1], 0.f);
        *(unsigned*)(xh + (size_t)node * HID + c0) =
            (unsigned)bf16_rne(r0) | ((unsigned)bf16_rne(r1) << 16);
        return;
    }
    int id = (blockIdx.x - NNODES / 4) * 256 + threadIdx.x;
    if (id < 4 * 144 * 128) {
        int l = id / (144 * 128);
        int rem = id % (144 * 128);
        int n = rem / 128, k = rem % 128;
        const float* W = Wg + (size_t)l * HID * HID;
        float v = 0.f;
        if (n < 128) {
            v = W[k * HID + n];
        } else if (n < 136) {
            int h = (n - 128) & 3;
            const float* av = ((n - 128) < 4 ? attS : attD) + l * HID + h * CHANS;
            for (int c = 0; c < CHANS; c++) v += W[k * HID + h * CHANS + c] * av[c];
        }
        unsigned short hh = bf16_rne(v);
        int t = n >> 4, bcol = n & 15;
        int ks = k >> 5, kq = (k >> 3) & 3, e = k & 7;
        size_t o = (size_t)l * (144 * 128) + (size_t)(((t * 4 + ks) * 64) + (kq * 16 + bcol)) * 8 + e;
        wh[o] = hh;
        wl[o] = bf16_rne(v - bf2f(hh));
        return;
    }
    id -= 4 * 144 * 128;
    if (id < 24576) {
        int n, k;
        float v;
        unsigned short *dh, *dl;
        if (id < 16384) {
            n = id / 128; k = id % 128;
            v = pW1[k * 128 + n];
            dh = w1h; dl = w1l;
        } else {
            int j = id - 16384;
            n = j / 128; k = j % 128;
            v = pW2[k * 64 + n];
            dh = w2h; dl = w2l;
        }
        unsigned short hh = bf16_rne(v);
        int t = n >> 4, bcol = n & 15;
        int ks = k >> 5, kq = (k >> 3) & 3, e = k & 7;
        size_t o = (size_t)(((t * 4 + ks) * 64) + (kq * 16 + bcol)) * 8 + e;
        dh[o] = hh;
        dl[o] = bf16_rne(v - bf2f(hh));
        return;
    }
    id -= 24576;
    if (id < 16384) {
        int t = id >> 7, k = id & 127;
        w1t[t * 128 + k] = vW1[k * 128 + t];
    } else if (id < 24576) {
        int j = id - 16384;
        int t = j >> 7, k = j & 127;
        w2t[t * 128 + k] = vW2[k * 64 + t];
    }
}

// ---------------- MFMA GEMM, K=128, 2-product (Ah*Bh + Ah*Bl) ----
// SINGLE-PHASE staging: entire B panel (NT*8 KB) staged via global_load_lds at once
// (9 chunks/wave in flight), ONE barrier pair -> one latency exposure per block
// instead of two. LDS = NT*8KB (73.7KB at NT=9) -> 2 blocks/CU.
template <int NT, int EPI>
__global__ __launch_bounds__(512, 4) void mfma_gemm(
    const unsigned short* __restrict__ Ah,
    const unsigned short* __restrict__ Bh, const unsigned short* __restrict__ Bl,
    const float* __restrict__ bias,
    unsigned short* __restrict__ outH,
    float* __restrict__ a_s, float* __restrict__ a_d,
    const float* __restrict__ wfin, const float* __restrict__ bfin,
    float* __restrict__ outF)
{
    __shared__ unsigned short lds[NT * 4096];

    int tid = threadIdx.x;
    int wid = tid >> 6, l = tid & 63;
    int row = blockIdx.x * 128 + wid * 16 + (l & 15);
    int kg = (l >> 4) * 8;

    // stage ALL of B: chunk c (1KB) = frag (t*4+ks), half lo; wave w takes c = w, w+8, ...
    for (int c = wid; c < 8 * NT; c += 8) {
        int fr = c >> 1, lo = c & 1;
        const unsigned short* src = (lo ? Bl : Bh) + ((size_t)fr << 9) + ((unsigned)l << 3);
        gload_lds16(src, &lds[(size_t)c << 9]);
    }

    const unsigned short* arh = Ah + (size_t)row * 128 + kg;
    bf16x8 afh[4];
#pragma unroll
    for (int ks = 0; ks < 4; ks++) afh[ks] = *(const bf16x8*)(arh + ks * 32);

    f32x4 acc[NT];
#pragma unroll
    for (int t = 0; t < NT; t++) acc[t] = (f32x4){0.f, 0.f, 0.f, 0.f};

    __syncthreads();   // drains vmcnt (global_load_lds) once; LDS fully populated

#pragma unroll
    for (int ks = 0; ks < 4; ks++) {
#pragma unroll
        for (int t = 0; t < NT; t++) {
            const unsigned short* bp = &lds[(((t * 4 + ks) << 1) << 9) + (l << 3)];
            bf16x8 bh  = *(const bf16x8*)bp;
            bf16x8 blo = *(const bf16x8*)(bp + 512);
            acc[t] = __builtin_amdgcn_mfma_f32_16x16x32_bf16(afh[ks], bh,  acc[t], 0, 0, 0);
            acc[t] = __builtin_amdgcn_mfma_f32_16x16x32_bf16(afh[ks], blo, acc[t], 0, 0, 0);
        }
    }

    // C/D layout: col = lane&15, row = (lane>>4)*4 + reg   [HW-verified]
    int ecol = l & 15;
    int er0 = blockIdx.x * 128 + wid * 16 + ((l >> 4) << 2);

    if constexpr (EPI == 0) {
#pragma unroll
        for (int t = 0; t < 8; t++)
#pragma unroll
            for (int j = 0; j < 4; j++)
                outH[(size_t)(er0 + j) * 128 + t * 16 + ecol] = bf16_rne(acc[t][j]);
#pragma unroll
        for (int j = 0; j < 4; j++) {
            float v = acc[8][j];
            if (ecol < 4)      a_s[(er0 + j) * 4 + ecol] = v;
            else if (ecol < 8) a_d[(er0 + j) * 4 + (ecol - 4)] = v;
        }
    } else if constexpr (EPI == 1) {
#pragma unroll
        for (int t = 0; t < NT; t++)
#pragma unroll
            for (int j = 0; j < 4; j++) {
                float v = fmaxf(acc[t][j] + bias[t * 16 + ecol], 0.f);
                outH[(size_t)(er0 + j) * 128 + t * 16 + ecol] = bf16_rne(v);
            }
    } else {
        float p0[4], p1[4];
#pragma unroll
        for (int j = 0; j < 4; j++) { p0[j] = 0.f; p1[j] = 0.f; }
#pragma unroll
        for (int t = 0; t < NT; t++) {
            int cc = t * 16 + ecol;
            float w0 = wfin[cc * 2 + 0], w1 = wfin[cc * 2 + 1];
#pragma unroll
            for (int j = 0; j < 4; j++) {
                float v = fmaxf(acc[t][j] + bias[cc], 0.f);
                p0[j] = fmaf(v, w0, p0[j]);
                p1[j] = fmaf(v, w1, p1[j]);
            }
        }
#pragma unroll
        for (int m = 1; m < 16; m <<= 1)
#pragma unroll
            for (int j = 0; j < 4; j++) {
                p0[j] += __shfl_xor(p0[j], m, 64);
                p1[j] += __shfl_xor(p1[j], m, 64);
            }
        if (ecol == 0) {
            float b0 = bfin[0], b1 = bfin[1];
#pragma unroll
            for (int j = 0; j < 4; j++) {
                outF[(er0 + j) * 2 + 0] = p0[j] + b0;
                outF[(er0 + j) * 2 + 1] = p1[j] + b1;
            }
        }
    }
}

// ------- fused: per-dst softmax (no-max, __expf) + 8-wide ILP aggregate + epilogue ----
__global__ __launch_bounds__(256, 8) void gat_agg(
    const unsigned short* __restrict__ hb, const float* __restrict__ a_s,
    const float* __restrict__ a_d, const int* __restrict__ offs,
    const int* __restrict__ col, const float* __restrict__ bgl,
    const float* __restrict__ gl, const float* __restrict__ bl,
    unsigned short* __restrict__ xh)
{
    __shared__ int2 whs[4][4][64];   // [wave][head][edge] = {w_bits, src}
    int wv = threadIdx.x >> 6;
    int lane = threadIdx.x & 63;
    int node = blockIdx.x * 4 + wv;
    int s = offs[node], e = offs[node + 1];
    int deg = e - s;
    float4 ad = *(const float4*)(a_d + (size_t)node * 4);

    int c0 = 2 * lane, c1 = 2 * lane + 1;
    int head = lane >> 4;
    float acc0 = 0.f, acc1 = 0.f;
    float den = 1e-16f;

    if (deg <= 64) {
        int src = 0;
        float e0 = 0.f, e1 = 0.f, e2 = 0.f, e3 = 0.f;
        if (lane < deg) {
            src = col[s + lane];
            float4 as = *(const float4*)(a_s + (size_t)src * 4);
            float s0 = as.x + ad.x; s0 = fmaxf(s0, 0.2f * s0);
            float s1 = as.y + ad.y; s1 = fmaxf(s1, 0.2f * s1);
            float s2 = as.z + ad.z; s2 = fmaxf(s2, 0.2f * s2);
            float s3 = as.w + ad.w; s3 = fmaxf(s3, 0.2f * s3);
            e0 = __expf(s0); e1 = __expf(s1); e2 = __expf(s2); e3 = __expf(s3);
        }
        whs[wv][0][lane] = make_int2(__float_as_int(e0), src);
        whs[wv][1][lane] = make_int2(__float_as_int(e1), src);
        whs[wv][2][lane] = make_int2(__float_as_int(e2), src);
        whs[wv][3][lane] = make_int2(__float_as_int(e3), src);
        // same-wave LDS RAW: no barrier needed. 8-wide batch: 8 independent gathers.
        const int2* wrow = &whs[wv][head][0];
        int dg8 = (deg + 7) & ~7;
        for (int j = 0; j < dg8; j += 8) {
            int2 q[8];
#pragma unroll
            for (int u = 0; u < 8; u++) q[u] = wrow[j + u];
            unsigned hv[8];
#pragma unroll
            for (int u = 0; u < 8; u++)
                hv[u] = *(const unsigned*)(hb + (((unsigned)q[u].y << 7) + (unsigned)c0));
#pragma unroll
            for (int u = 0; u < 8; u++) {
                float w = __int_as_float(q[u].x);
                den += w;
                acc0 = fmaf(w, __uint_as_float(hv[u] << 16), acc0);
                acc1 = fmaf(w, __uint_as_float(hv[u] & 0xffff0000u), acc1);
            }
        }
    } else {
        for (int j = s; j < e; j++) {
            int src = col[j];
            float4 as = *(const float4*)(a_s + (size_t)src * 4);
            float sh = (head == 0) ? (as.x + ad.x) : (head == 1) ? (as.y + ad.y)
                     : (head == 2) ? (as.z + ad.z) : (as.w + ad.w);
            sh = fmaxf(sh, 0.2f * sh);
            float wj = __expf(sh);
            den += wj;
            unsigned hv = *(const unsigned*)(hb + (((unsigned)src << 7) + (unsigned)c0));
            acc0 = fmaf(wj, __uint_as_float(hv << 16), acc0);
            acc1 = fmaf(wj, __uint_as_float(hv & 0xffff0000u), acc1);
        }
    }
    float inv = 1.f / den;
    acc0 *= inv;
    acc1 *= inv;

    // epilogue: + bias, ReLU, residual (bf16 x), LayerNorm, write x
    float o0 = fmaxf(acc0 + bgl[c0], 0.f);
    float o1 = fmaxf(acc1 + bgl[c1], 0.f);
    size_t xi = (size_t)node * HID;
    unsigned ph = *(const unsigned*)(xh + xi + c0);
    float t0 = __uint_as_float(ph << 16) + o0;
    float t1 = __uint_as_float(ph & 0xffff0000u) + o1;
    float mu = wave_reduce_sum(t0 + t1) * (1.f / 128.f);
    float e0 = t0 - mu, e1 = t1 - mu;
    float var = wave_reduce_sum(e0 * e0 + e1 * e1) * (1.f / 128.f);
    float r = 1.f / sqrtf(var + 1e-5f);
    float r0 = e0 * r * gl[c0] + bl[c0];
    float r1 = e1 * r * gl[c1] + bl[c1];
    *(unsigned*)(xh + xi + c0) = (unsigned)bf16_rne(r0) | ((unsigned)bf16_rne(r1) << 16);
}

// ---------------- value head ----------------
__global__ void pool_sum(const unsigned short* __restrict__ xh, float* __restrict__ partial) {
    int t = threadIdx.x;
    int base = blockIdx.x * 256;
    float s = 0.f;
    for (int i = 0; i < 256; i++)
        s += bf2f(xh[(size_t)(base + i) * HID + t]);
    partial[blockIdx.x * 128 + t] = s;
}

__global__ void value_mlp(const float* __restrict__ partial,
                          const float* __restrict__ w1t, const float* __restrict__ b1,
                          const float* __restrict__ w2t, const float* __restrict__ b2,
                          const float* __restrict__ W3, const float* __restrict__ b3,
                          float* __restrict__ out)
{
    __shared__ float p[128], h1[128], h2[64];
    int t = threadIdx.x;   // 128
    float s = 0.f;
    for (int i = 0; i < 256; i++) s += partial[i * 128 + t];
    p[t] = s * (1.f / (float)NNODES);
    __syncthreads();
    float a = b1[t];
    const float4* wr = (const float4*)(w1t + (size_t)t * 128);
#pragma unroll
    for (int k4 = 0; k4 < 32; k4++) {
        float4 w = wr[k4];
        a += p[4 * k4] * w.x + p[4 * k4 + 1] * w.y + p[4 * k4 + 2] * w.z + p[4 * k4 + 3] * w.w;
    }
    h1[t] = fmaxf(a, 0.f);
    __syncthreads();
    if (t < 64) {
        float a2 = b2[t];
        const float4* wr2 = (const float4*)(w2t + (size_t)t * 128);
#pragma unroll
        for (int k4 = 0; k4 < 32; k4++) {
            float4 w = wr2[k4];
            a2 += h1[4 * k4] * w.x + h1[4 * k4 + 1] * w.y + h1[4 * k4 + 2] * w.z + h1[4 * k4 + 3] * w.w;
        }
        h2[t] = fmaxf(a2, 0.f);
    }
    __syncthreads();
    if (t == 0) {
        float v = b3[0];
        for (int k = 0; k < 64; k++) v = fmaf(h2[k], W3[k], v);
        out[NDATA * 2] = v;
    }
}

extern "C" void kernel_launch(void* const* d_in, const int* in_sizes, int n_in,
                              void* d_out, int out_size, void* d_ws, size_t ws_size,
                              hipStream_t stream)
{
    const float* feat  = (const float*)d_in[0];
    const int*   ei    = (const int*)d_in[1];
    const float* W_emb = (const float*)d_in[2];
    const float* b_emb = (const float*)d_in[3];
    const float* ln0g  = (const float*)d_in[4];
    const float* ln0b  = (const float*)d_in[5];
    const float* Wg    = (const float*)d_in[6];
    const float* att_s = (const float*)d_in[7];
    const float* att_d = (const float*)d_in[8];
    const float* bg    = (const float*)d_in[9];
    const float* lng   = (const float*)d_in[10];
    const float* lnb   = (const float*)d_in[11];
    const float* pW1 = (const float*)d_in[12]; const float* pb1 = (const float*)d_in[13];
    const float* pW2 = (const float*)d_in[14]; const float* pb2 = (const float*)d_in[15];
    const float* pW3 = (const float*)d_in[16]; const float* pb3 = (const float*)d_in[17];
    const float* vW1 = (const float*)d_in[18]; const float* vb1 = (const float*)d_in[19];
    const float* vW2 = (const float*)d_in[20]; const float* vb2 = (const float*)d_in[21];
    const float* vW3 = (const float*)d_in[22]; const float* vb3 = (const float*)d_in[23];
    float* out = (float*)d_out;
    int Eo = in_sizes[1] / 2;

    // workspace layout
    unsigned short* xh = (unsigned short*)d_ws;              // 65536*128 bf16
    unsigned short* hb = xh + (size_t)NNODES * HID;          // h bf16; reused as ph1h
    float* a_s = (float*)(hb + (size_t)NNODES * HID);
    float* a_d = a_s + NNODES * HEADS;
    unsigned short* wgt_h = (unsigned short*)(a_d + NNODES * HEADS);  // 4*144*128
    unsigned short* wgt_l = wgt_h + 4 * 144 * 128;
    unsigned short* pw1h  = wgt_l + 4 * 144 * 128;           // 128*128
    unsigned short* pw1l  = pw1h + 128 * 128;
    unsigned short* pw2h  = pw1l + 128 * 128;                // 64*128
    unsigned short* pw2l  = pw2h + 64 * 128;
    float* w1t  = (float*)(pw2l + 64 * 128);                 // 128*128 f32
    float* w2t  = w1t + 128 * 128;                           // 64*128 f32
    float* partial = w2t + 64 * 128;                         // 256*128 f32
    int* deg    = (int*)(partial + 256 * 128);
    int* offs   = deg + NNODES;
    int* cursor = offs + NNODES + 2;
    int* bsum   = cursor + NNODES;
    int* col    = bsum + 256;
    unsigned short* ph1h = hb;

    // merged embedding + weight prep (embed blocks first, then 480 prep blocks)
    prep_embed<<<NNODES / 4 + 480, 256, 0, stream>>>(
        feat, W_emb, b_emb, ln0g, ln0b, xh,
        Wg, att_s, att_d, pW1, pW2, vW1, vW2,
        wgt_h, wgt_l, pw1h, pw1l, pw2h, pw2l, w1t, w2t);

    // CSR build (dst -> src list), self-loops included (+1 folded into scan1)
    hipMemsetAsync(deg, 0, (size_t)NNODES * 4, stream);
    hist_kernel<<<(Eo + 255) / 256, 256, 0, stream>>>(ei, deg, Eo);
    scan1<<<256, 256, 0, stream>>>(deg, offs, bsum);
    scan3<<<256, 256, 0, stream>>>(offs, bsum, cursor, Eo);
    fill_kernel<<<(Eo + NNODES + 255) / 256, 256, 0, stream>>>(ei, cursor, col, Eo);

    // GAT layers
    for (int l = 0; l < LAYERS; l++) {
        mfma_gemm<9, 0><<<NNODES / 128, 512, 0, stream>>>(
            xh, wgt_h + (size_t)l * 144 * 128, wgt_l + (size_t)l * 144 * 128,
            nullptr, hb, a_s, a_d, nullptr, nullptr, nullptr);
        gat_agg<<<NNODES / 4, 256, 0, stream>>>(
            hb, a_s, a_d, offs, col, bg + l * HID, lng + l * HID, lnb + l * HID, xh);
    }

    // policy head: GEMM1 -> bf16-hi ph1; GEMM2 + fused [64,2] -> logits
    mfma_gemm<8, 1><<<NDATA / 128, 512, 0, stream>>>(
        xh, pw1h, pw1l, pb1, ph1h, nullptr, nullptr, nullptr, nullptr, nullptr);
    mfma_gemm<4, 2><<<NDATA / 128, 512, 0, stream>>>(
        ph1h, pw2h, pw2l, pb2, nullptr, nullptr, nullptr, pW3, pb3, out);

    // value head
    pool_sum<<<256, 128, 0, stream>>>(xh, partial);
    value_mlp<<<1, 128, 0, stream>>>(partial, w1t, vb1, w2t, vb2, vW3, vb3, out);
}